// Round 1
// baseline (1328.358 us; speedup 1.0000x reference)
//
#include <hip/hip_runtime.h>
#include <math.h>

#define B_  4096
#define C_  64
#define LQ_ 32
#define D_  128
#define H_  192

// ---------------------------------------------------------------------------
// Kernel 1: table encoder
//   per (b,c): te = relu(relu([hdr,tbl] @ W1 + b1) @ W2 + b2) * mask
//   te_sum[b] = sum_c te / num_cols[b];  te_out[b] = l2norm(te_sum)
// One block per b (4096 blocks, 256 threads). 16-row batches (4 per block).
// GEMM1: thread = (col 0..63, rg 0..3): 3 j-cols {col,col+64,col+128} x 4 rows.
// GEMM2: 2 j-cols {col,col+64} x 4 rows.
// LDS reads are wave-uniform broadcasts (whole wave shares rg).
// ---------------------------------------------------------------------------
__global__ __launch_bounds__(256) void table_kernel(
    const float* __restrict__ header, const float* __restrict__ tword,
    const float* __restrict__ masks, const int* __restrict__ num_cols,
    const float* __restrict__ W1, const float* __restrict__ b1,
    const float* __restrict__ W2, const float* __restrict__ b2,
    float* __restrict__ te_out)
{
    const int b   = blockIdx.x;
    const int tid = threadIdx.x;
    const int col = tid & 63;
    const int rg  = tid >> 6;          // 0..3 -> rows rg*4 .. rg*4+3

    __shared__ float flat[16][256];    // 16 KB
    __shared__ float hbuf[16][192];    // 12 KB
    __shared__ float part[4][128];     // 2 KB
    __shared__ float red[128];         // 0.5 KB

    float tacc0 = 0.f, tacc1 = 0.f;    // te_sum partial for j2 = col, col+64

    for (int cb = 0; cb < 4; ++cb) {
        // ---- stage flat[16][256] = [header | tword] rows cb*16 .. cb*16+15
        #pragma unroll
        for (int i = 0; i < 4; ++i) {
            int idx = tid + i * 256;       // 0..1023 float4 slots
            int r   = idx >> 6;            // 0..15
            int k4  = idx & 63;            // 0..63
            int c   = cb * 16 + r;
            const float* src = (k4 < 32)
                ? &header[(size_t)(b * C_ + c) * D_ + k4 * 4]
                : &tword [(size_t)(b * C_ + c) * D_ + (k4 - 32) * 4];
            *(float4*)&flat[r][k4 * 4] = *(const float4*)src;
        }
        __syncthreads();   // flat ready; also guarantees prev GEMM2 done with hbuf

        // ---- GEMM1: h[r][j] = relu(b1[j] + sum_k flat[r][k] * W1[k][j])
        float acc[3][4];
        #pragma unroll
        for (int jj = 0; jj < 3; ++jj) {
            float bb = b1[col + 64 * jj];
            #pragma unroll
            for (int rr = 0; rr < 4; ++rr) acc[jj][rr] = bb;
        }
        #pragma unroll 2
        for (int k4 = 0; k4 < 64; ++k4) {
            float xr[4][4];
            #pragma unroll
            for (int rr = 0; rr < 4; ++rr) {
                float4 t = *(const float4*)&flat[rg * 4 + rr][k4 * 4];
                xr[rr][0] = t.x; xr[rr][1] = t.y; xr[rr][2] = t.z; xr[rr][3] = t.w;
            }
            #pragma unroll
            for (int kk = 0; kk < 4; ++kk) {
                int k = k4 * 4 + kk;
                float w0 = W1[k * H_ + col];
                float w1 = W1[k * H_ + col + 64];
                float w2 = W1[k * H_ + col + 128];
                #pragma unroll
                for (int rr = 0; rr < 4; ++rr) {
                    acc[0][rr] = fmaf(xr[rr][kk], w0, acc[0][rr]);
                    acc[1][rr] = fmaf(xr[rr][kk], w1, acc[1][rr]);
                    acc[2][rr] = fmaf(xr[rr][kk], w2, acc[2][rr]);
                }
            }
        }
        #pragma unroll
        for (int jj = 0; jj < 3; ++jj)
            #pragma unroll
            for (int rr = 0; rr < 4; ++rr)
                hbuf[rg * 4 + rr][col + 64 * jj] = fmaxf(acc[jj][rr], 0.f);
        __syncthreads();   // hbuf ready

        // ---- GEMM2: te[r][j2] = relu(b2[j2] + sum_k h[r][k] * W2[k][j2])
        float acc2[2][4];
        {
            float bb0 = b2[col], bb1 = b2[col + 64];
            #pragma unroll
            for (int rr = 0; rr < 4; ++rr) { acc2[0][rr] = bb0; acc2[1][rr] = bb1; }
        }
        #pragma unroll 2
        for (int k4 = 0; k4 < 48; ++k4) {
            float hr[4][4];
            #pragma unroll
            for (int rr = 0; rr < 4; ++rr) {
                float4 t = *(const float4*)&hbuf[rg * 4 + rr][k4 * 4];
                hr[rr][0] = t.x; hr[rr][1] = t.y; hr[rr][2] = t.z; hr[rr][3] = t.w;
            }
            #pragma unroll
            for (int kk = 0; kk < 4; ++kk) {
                int k = k4 * 4 + kk;
                float w0 = W2[k * D_ + col];
                float w1 = W2[k * D_ + col + 64];
                #pragma unroll
                for (int rr = 0; rr < 4; ++rr) {
                    acc2[0][rr] = fmaf(hr[rr][kk], w0, acc2[0][rr]);
                    acc2[1][rr] = fmaf(hr[rr][kk], w1, acc2[1][rr]);
                }
            }
        }
        #pragma unroll
        for (int rr = 0; rr < 4; ++rr) {
            int c = cb * 16 + rg * 4 + rr;
            float m = masks[b * C_ + c];
            tacc0 += fmaxf(acc2[0][rr], 0.f) * m;
            tacc1 += fmaxf(acc2[1][rr], 0.f) * m;
        }
        // next loop iteration's stage+sync protects flat/hbuf
    }

    // ---- reduce across rg groups, divide, l2norm
    part[rg][col]      = tacc0;
    part[rg][col + 64] = tacc1;
    __syncthreads();
    float v = 0.f;
    if (tid < 128) {
        v = part[0][tid] + part[1][tid] + part[2][tid] + part[3][tid];
        v /= (float)num_cols[b];
        red[tid] = v * v;
    }
    __syncthreads();
    for (int s = 64; s > 0; s >>= 1) {
        if (tid < s) red[tid] += red[tid + s];
        __syncthreads();
    }
    if (tid < 128) {
        float inv = 1.f / sqrtf(fmaxf(red[0], 1e-12f));
        te_out[(size_t)b * D_ + tid] = v * inv;
    }
}

// ---------------------------------------------------------------------------
// Kernel 2: masked LSTM over LQ=32 steps.  16 batch rows per block,
// 512 threads (8 waves), 256 blocks.
// Matmul phase: thread = (col 0..255, rg 0..1); rg splits K (k-half),
// thread accumulates z for j = {col, col+256} over all 16 rows.
// Gate phase: thread = (d 0..127, rq 0..3): hidden d for rows rq*4..rq*4+3,
// cell state in registers.
// ---------------------------------------------------------------------------
__global__ __launch_bounds__(512) void lstm_kernel(
    const float* __restrict__ q, const int* __restrict__ lengths,
    const float* __restrict__ Wx, const float* __restrict__ Wh,
    const float* __restrict__ bl, float* __restrict__ qe_out)
{
    const int tid = threadIdx.x;
    const int b0  = blockIdx.x * 16;
    const int col = tid & 255;
    const int rg  = tid >> 8;          // k-half: k in [rg*64, rg*64+64)
    const int k0  = rg * 64;

    __shared__ float xs[16][128];      // 8 KB
    __shared__ float hs[16][128];      // 8 KB
    __shared__ float zs[16][512];      // 32 KB

    for (int i = tid; i < 16 * 128; i += 512) ((float*)hs)[i] = 0.f;

    // gate-thread state
    const int d     = tid & 127;
    const int rbase = (tid >> 7) * 4;
    float creg[4] = {0.f, 0.f, 0.f, 0.f};
    int len4[4];
    #pragma unroll
    for (int rr = 0; rr < 4; ++rr) len4[rr] = lengths[b0 + rbase + rr];

    const float bj0 = bl[col], bj1 = bl[col + 256];
    __syncthreads();

    for (int t = 0; t < LQ_; ++t) {
        // ---- stage x_t (one float4 per thread)
        {
            int r  = tid >> 5;
            int k4 = tid & 31;
            *(float4*)&xs[r][k4 * 4] =
                *(const float4*)&q[((size_t)(b0 + r) * LQ_ + t) * D_ + k4 * 4];
        }
        __syncthreads();

        // ---- matmul: z[r][j] partial over this thread's k-half
        float z0[16], z1[16];
        #pragma unroll
        for (int r = 0; r < 16; ++r) {
            z0[r] = (rg == 0) ? bj0 : 0.f;
            z1[r] = (rg == 0) ? bj1 : 0.f;
        }
        for (int k4 = 0; k4 < 16; ++k4) {
            int kb = k0 + k4 * 4;
            float wx0[4], wx1[4], wh0[4], wh1[4];
            #pragma unroll
            for (int kk = 0; kk < 4; ++kk) {
                wx0[kk] = Wx[(kb + kk) * 512 + col];
                wx1[kk] = Wx[(kb + kk) * 512 + col + 256];
                wh0[kk] = Wh[(kb + kk) * 512 + col];
                wh1[kk] = Wh[(kb + kk) * 512 + col + 256];
            }
            #pragma unroll
            for (int r = 0; r < 16; ++r) {
                float4 xt = *(const float4*)&xs[r][kb];
                float4 ht = *(const float4*)&hs[r][kb];
                float xa[4] = {xt.x, xt.y, xt.z, xt.w};
                float ha[4] = {ht.x, ht.y, ht.z, ht.w};
                #pragma unroll
                for (int kk = 0; kk < 4; ++kk) {
                    z0[r] = fmaf(xa[kk], wx0[kk], z0[r]);
                    z0[r] = fmaf(ha[kk], wh0[kk], z0[r]);
                    z1[r] = fmaf(xa[kk], wx1[kk], z1[r]);
                    z1[r] = fmaf(ha[kk], wh1[kk], z1[r]);
                }
            }
        }
        // combine the two k-halves in LDS
        if (rg == 0) {
            #pragma unroll
            for (int r = 0; r < 16; ++r) { zs[r][col] = z0[r]; zs[r][col + 256] = z1[r]; }
        }
        __syncthreads();
        if (rg == 1) {
            #pragma unroll
            for (int r = 0; r < 16; ++r) { zs[r][col] += z0[r]; zs[r][col + 256] += z1[r]; }
        }
        __syncthreads();

        // ---- gates (all 512 threads: hidden d, 4 rows each)
        #pragma unroll
        for (int rr = 0; rr < 4; ++rr) {
            int r = rbase + rr;
            if (t < len4[rr]) {            // wave-uniform branch
                float zi = zs[r][d];
                float zf = zs[r][D_ + d];
                float zg = zs[r][2 * D_ + d];
                float zo = zs[r][3 * D_ + d];
                float iv = 1.f / (1.f + expf(-zi));
                float fv = 1.f / (1.f + expf(-zf));
                float gv = fmaxf(zg, 0.f);
                float ov = 1.f / (1.f + expf(-zo));
                float cn = fmaf(fv, creg[rr], iv * gv);
                creg[rr] = cn;
                hs[r][d] = ov * fmaxf(cn, 0.f);
            }
        }
        __syncthreads();
    }

    // ---- l2norm each row, write qe
    {
        int r = tid >> 5;
        int l = tid & 31;
        float p = 0.f;
        #pragma unroll
        for (int m = 0; m < 4; ++m) { float hv = hs[r][l + 32 * m]; p = fmaf(hv, hv, p); }
        #pragma unroll
        for (int s = 16; s > 0; s >>= 1) p += __shfl_xor(p, s, 32);
        float inv = 1.f / sqrtf(fmaxf(p, 1e-12f));
        #pragma unroll
        for (int m = 0; m < 4; ++m)
            qe_out[(size_t)(b0 + r) * D_ + l + 32 * m] = hs[r][l + 32 * m] * inv;
    }
}

// ---------------------------------------------------------------------------
// Kernel 3: per-sample contrastive loss + per-block partial sum
// ---------------------------------------------------------------------------
__global__ __launch_bounds__(256) void loss_kernel(
    const float* __restrict__ te, const float* __restrict__ qe,
    const float* __restrict__ labels, float* __restrict__ partial)
{
    const int tid = threadIdx.x;
    const int b   = blockIdx.x * 256 + tid;
    float dsum = 0.f;
    #pragma unroll 8
    for (int k4 = 0; k4 < 32; ++k4) {
        float4 a = *(const float4*)&qe[(size_t)b * D_ + k4 * 4];
        float4 c = *(const float4*)&te[(size_t)b * D_ + k4 * 4];
        float dx = a.x - c.x, dy = a.y - c.y, dz = a.z - c.z, dw = a.w - c.w;
        dsum += dx * dx + dy * dy + dz * dz + dw * dw;
    }
    float lab = labels[b];
    float ds  = sqrtf(dsum);
    float ml  = fmaxf(0.f, 1.f - ds);
    float loss = lab * dsum + (1.f - lab) * ml * ml;

    __shared__ float red[256];
    red[tid] = loss;
    __syncthreads();
    for (int s = 128; s > 0; s >>= 1) {
        if (tid < s) red[tid] += red[tid + s];
        __syncthreads();
    }
    if (tid == 0) partial[blockIdx.x] = red[0];
}

__global__ void final_kernel(const float* __restrict__ partial, float* __restrict__ out)
{
    const int tid = threadIdx.x;   // 64 threads
    float v = (tid < 16) ? partial[tid] : 0.f;
    #pragma unroll
    for (int s = 32; s > 0; s >>= 1) v += __shfl_xor(v, s, 64);
    if (tid == 0) out[0] = 0.5f * v / (float)B_;
}

// ---------------------------------------------------------------------------
extern "C" void kernel_launch(void* const* d_in, const int* in_sizes, int n_in,
                              void* d_out, int out_size, void* d_ws, size_t ws_size,
                              hipStream_t stream)
{
    const float* q      = (const float*)d_in[0];
    const int*   qlen   = (const int*)d_in[1];
    const float* header = (const float*)d_in[2];
    const float* tword  = (const float*)d_in[3];
    const int*   ncols  = (const int*)d_in[4];
    const float* masks  = (const float*)d_in[5];
    const float* labels = (const float*)d_in[6];
    const float* W1     = (const float*)d_in[7];
    const float* b1     = (const float*)d_in[8];
    const float* W2     = (const float*)d_in[9];
    const float* b2     = (const float*)d_in[10];
    const float* Wx     = (const float*)d_in[11];
    const float* Wh     = (const float*)d_in[12];
    const float* bl     = (const float*)d_in[13];
    float* out = (float*)d_out;

    float* te      = (float*)d_ws;
    float* qe      = te + (size_t)B_ * D_;
    float* partial = qe + (size_t)B_ * D_;

    table_kernel<<<B_, 256, 0, stream>>>(header, tword, masks, ncols, W1, b1, W2, b2, te);
    lstm_kernel<<<B_ / 16, 512, 0, stream>>>(q, qlen, Wx, Wh, bl, qe);
    loss_kernel<<<B_ / 256, 256, 0, stream>>>(te, qe, labels, partial);
    final_kernel<<<1, 64, 0, stream>>>(partial, out);
}

// Round 2
// 194.655 us; speedup vs baseline: 6.8242x; 6.8242x over previous
//
#include <hip/hip_runtime.h>
#include <math.h>

#define B_  4096
#define C_  64
#define LQ_ 32
#define D_  128
#define H_  192

typedef __attribute__((ext_vector_type(8))) short bf16x8;
typedef __attribute__((ext_vector_type(4))) float f32x4;

__device__ inline unsigned cvt_pk_bf16(float lo, float hi) {
    unsigned r;
    asm("v_cvt_pk_bf16_f32 %0, %1, %2" : "=v"(r) : "v"(lo), "v"(hi));
    return r;
}
__device__ inline short f2b(float x) { return (short)(cvt_pk_bf16(x, x) & 0xffff); }
__device__ inline float sigm(float x) { return 1.f / (1.f + __expf(-x)); }

// ---------------------------------------------------------------------------
// Prep: transpose + convert weights to bf16.
//   W1T [192][256]  (j-major), W2T [128][192],
//   WTl [512][256]: row p = w*64 + g*16 + jj  <->  orig col j = g*128 + w*16 + jj,
//                   k<128 -> Wx[k][j], k>=128 -> Wh[k-128][j]
// ---------------------------------------------------------------------------
__global__ __launch_bounds__(256) void prep_kernel(
    const float* __restrict__ W1, const float* __restrict__ W2,
    const float* __restrict__ Wx, const float* __restrict__ Wh,
    short* __restrict__ W1T, short* __restrict__ W2T, short* __restrict__ WTl)
{
    int idx = blockIdx.x * 256 + threadIdx.x;   // 0 .. 131071
    if (idx < 192 * 256) {
        int j = idx >> 8, k = idx & 255;
        W1T[idx] = f2b(W1[k * H_ + j]);
    }
    if (idx < 128 * 192) {
        int j = idx / 192, k = idx - j * 192;
        W2T[idx] = f2b(W2[k * D_ + j]);
    }
    if (idx < 512 * 256) {
        int p = idx >> 8, k = idx & 255;
        int w = p >> 6, g = (p >> 4) & 3, jj = p & 15;
        int jo = g * 128 + w * 16 + jj;
        float v = (k < 128) ? Wx[k * 512 + jo] : Wh[(k - 128) * 512 + jo];
        WTl[idx] = f2b(v);
    }
}

// ---------------------------------------------------------------------------
// Table encoder: block = one b. 4 waves.
// GEMM1: [64][256]@[256][192] (MFMA 16x16x32), GEMM2: [64][192]@[192][128],
// fused mask * column-sum, /num_cols, l2norm.
// LDS tiles XOR-swizzled: byte ^= (row&7)<<4 (T2).
// ---------------------------------------------------------------------------
__global__ __launch_bounds__(256, 2) void table_kernel(
    const float* __restrict__ header, const float* __restrict__ tword,
    const float* __restrict__ masks, const int* __restrict__ num_cols,
    const short* __restrict__ W1T, const float* __restrict__ b1,
    const short* __restrict__ W2T, const float* __restrict__ b2,
    float* __restrict__ te_out)
{
    const int b   = blockIdx.x;
    const int tid = threadIdx.x;
    const int w   = tid >> 6;
    const int l   = tid & 63;
    const int lg  = l >> 4;
    const int ln  = l & 15;

    __shared__ __align__(16) short flat_s[64 * 256];  // 32 KB, swizzled
    __shared__ __align__(16) short h_s[64 * 192];     // 24 KB, swizzled
    __shared__ float msk[64];
    __shared__ float redv[128];
    __shared__ float redq[128];

    // W1 fragments resident (wave w owns h-cols [w*48, w*48+48))
    bf16x8 bw1[3][8];
    #pragma unroll
    for (int ct = 0; ct < 3; ++ct) {
        int j = w * 48 + ct * 16 + ln;
        #pragma unroll
        for (int ks = 0; ks < 8; ++ks)
            bw1[ct][ks] = *(const bf16x8*)&W1T[j * 256 + ks * 32 + lg * 8];
    }
    float bias1[3];
    #pragma unroll
    for (int ct = 0; ct < 3; ++ct) bias1[ct] = b1[w * 48 + ct * 16 + ln];

    // stage [header|tword] -> flat_s bf16 (swizzled)
    #pragma unroll
    for (int i = 0; i < 16; ++i) {
        int chunk = i * 256 + tid;           // 64 rows x 64 8B-chunks
        int r = chunk >> 6, c = chunk & 63;
        const float* src = (c < 32)
            ? &header[((size_t)b * C_ + r) * D_ + c * 4]
            : &tword [((size_t)b * C_ + r) * D_ + (c - 32) * 4];
        float4 v = *(const float4*)src;
        uint2 p;
        p.x = cvt_pk_bf16(v.x, v.y);
        p.y = cvt_pk_bf16(v.z, v.w);
        *(uint2*)((char*)flat_s + r * 512 + ((c * 8) ^ ((r & 7) << 4))) = p;
    }
    if (tid < 64) msk[tid] = masks[b * C_ + tid];
    __syncthreads();

    // GEMM1 -> h_s (bias + relu fused)
    #pragma unroll
    for (int rt = 0; rt < 4; ++rt) {
        int row = rt * 16 + ln;
        bf16x8 a[8];
        #pragma unroll
        for (int ks = 0; ks < 8; ++ks)
            a[ks] = *(const bf16x8*)((char*)flat_s + row * 512 +
                                     ((ks * 64 + lg * 16) ^ ((row & 7) << 4)));
        f32x4 acc[3];
        #pragma unroll
        for (int ct = 0; ct < 3; ++ct)
            acc[ct] = (f32x4){bias1[ct], bias1[ct], bias1[ct], bias1[ct]};
        #pragma unroll
        for (int ks = 0; ks < 8; ++ks)
            #pragma unroll
            for (int ct = 0; ct < 3; ++ct)
                acc[ct] = __builtin_amdgcn_mfma_f32_16x16x32_bf16(a[ks], bw1[ct][ks], acc[ct], 0, 0, 0);
        #pragma unroll
        for (int ct = 0; ct < 3; ++ct) {
            int col = w * 48 + ct * 16 + ln;
            #pragma unroll
            for (int reg = 0; reg < 4; ++reg) {
                int orow = rt * 16 + lg * 4 + reg;   // D-row mapping
                *(short*)((char*)h_s + orow * 384 + ((col * 2) ^ ((orow & 7) << 4))) =
                    f2b(fmaxf(acc[ct][reg], 0.f));
            }
        }
    }
    __syncthreads();

    // GEMM2 + fused mask*column-sum (wave w owns te-cols [w*32, w*32+32))
    bf16x8 bw2[2][6];
    float bias2[2];
    #pragma unroll
    for (int ct = 0; ct < 2; ++ct) {
        int j = w * 32 + ct * 16 + ln;
        bias2[ct] = b2[j];
        #pragma unroll
        for (int ks = 0; ks < 6; ++ks)
            bw2[ct][ks] = *(const bf16x8*)&W2T[j * 192 + ks * 32 + lg * 8];
    }
    float csum[2] = {0.f, 0.f};
    #pragma unroll
    for (int rt = 0; rt < 4; ++rt) {
        int row = rt * 16 + ln;
        bf16x8 a[6];
        #pragma unroll
        for (int ks = 0; ks < 6; ++ks)
            a[ks] = *(const bf16x8*)((char*)h_s + row * 384 +
                                     ((ks * 64 + lg * 16) ^ ((row & 7) << 4)));
        f32x4 acc[2];
        #pragma unroll
        for (int ct = 0; ct < 2; ++ct)
            acc[ct] = (f32x4){bias2[ct], bias2[ct], bias2[ct], bias2[ct]};
        #pragma unroll
        for (int ks = 0; ks < 6; ++ks)
            #pragma unroll
            for (int ct = 0; ct < 2; ++ct)
                acc[ct] = __builtin_amdgcn_mfma_f32_16x16x32_bf16(a[ks], bw2[ct][ks], acc[ct], 0, 0, 0);
        #pragma unroll
        for (int ct = 0; ct < 2; ++ct)
            #pragma unroll
            for (int reg = 0; reg < 4; ++reg) {
                int orow = rt * 16 + lg * 4 + reg;
                csum[ct] = fmaf(fmaxf(acc[ct][reg], 0.f), msk[orow], csum[ct]);
            }
    }
    #pragma unroll
    for (int s = 16; s < 64; s <<= 1) {
        csum[0] += __shfl_xor(csum[0], s, 64);
        csum[1] += __shfl_xor(csum[1], s, 64);
    }
    float nc = (float)num_cols[b];
    if (l < 16) {
        redv[w * 32 + ln]      = csum[0] / nc;
        redv[w * 32 + 16 + ln] = csum[1] / nc;
    }
    __syncthreads();
    if (tid < 128) redq[tid] = redv[tid] * redv[tid];
    __syncthreads();
    for (int s = 64; s > 0; s >>= 1) {
        if (tid < s) redq[tid] += redq[tid + s];
        __syncthreads();
    }
    if (tid < 128) {
        float inv = rsqrtf(fmaxf(redq[0], 1e-12f));
        te_out[(size_t)b * D_ + tid] = redv[tid] * inv;
    }
}

// ---------------------------------------------------------------------------
// LSTM: 256 blocks x 512 threads (8 waves), 16 batch rows per block.
// z^T = WTl @ [x;h]^T via MFMA; wave w owns d in [w*16, w*16+16) for all
// four gates (WTl row permutation) -> gates fully wave-local, c/h in VGPRs.
// One barrier per step; xh double-buffered, XOR-swizzled.
// ---------------------------------------------------------------------------
__global__ __launch_bounds__(512, 2) void lstm_kernel(
    const float* __restrict__ q, const int* __restrict__ lengths,
    const short* __restrict__ WTl, const float* __restrict__ bl,
    float* __restrict__ qe_out)
{
    const int tid = threadIdx.x;
    const int b0  = blockIdx.x * 16;
    const int w   = tid >> 6;
    const int l   = tid & 63;
    const int lg  = l >> 4;
    const int ln  = l & 15;       // batch row within block
    const int d0  = w * 16 + lg * 4;

    __shared__ __align__(16) short xh[2][16 * 256];  // 2 x 8 KB, swizzled
    __shared__ float red8[8][16];

    // W fragments resident across all timesteps (128 VGPRs)
    bf16x8 wf[4][8];
    #pragma unroll
    for (int g = 0; g < 4; ++g)
        #pragma unroll
        for (int ks = 0; ks < 8; ++ks)
            wf[g][ks] = *(const bf16x8*)&WTl[(w * 64 + g * 16 + ln) * 256 + ks * 32 + lg * 8];
    float bias[4][4];
    #pragma unroll
    for (int g = 0; g < 4; ++g)
        #pragma unroll
        for (int reg = 0; reg < 4; ++reg)
            bias[g][reg] = bl[g * 128 + d0 + reg];

    float creg[4] = {0.f, 0.f, 0.f, 0.f};
    float hreg[4] = {0.f, 0.f, 0.f, 0.f};
    const int len = lengths[b0 + ln];
    const int sr = tid >> 5, sc = tid & 31;

    for (int t = 0; t < LQ_; ++t) {
        char* buf = (char*)xh[t & 1];
        // stage x_t (one float4 per thread)
        float4 v = *(const float4*)&q[((size_t)(b0 + sr) * LQ_ + t) * D_ + sc * 4];
        uint2 px; px.x = cvt_pk_bf16(v.x, v.y); px.y = cvt_pk_bf16(v.z, v.w);
        *(uint2*)(buf + sr * 512 + ((sc * 8) ^ ((sr & 7) << 4))) = px;
        // write h(t-1) (4 bf16 per lane)
        uint2 ph; ph.x = cvt_pk_bf16(hreg[0], hreg[1]); ph.y = cvt_pk_bf16(hreg[2], hreg[3]);
        *(uint2*)(buf + ln * 512 + ((256 + d0 * 2) ^ ((ln & 7) << 4))) = ph;
        __syncthreads();

        bf16x8 xf[8];
        #pragma unroll
        for (int ks = 0; ks < 8; ++ks)
            xf[ks] = *(const bf16x8*)(buf + ln * 512 + ((ks * 64 + lg * 16) ^ ((ln & 7) << 4)));
        f32x4 acc[4];
        #pragma unroll
        for (int g = 0; g < 4; ++g)
            acc[g] = (f32x4){bias[g][0], bias[g][1], bias[g][2], bias[g][3]};
        #pragma unroll
        for (int ks = 0; ks < 8; ++ks)
            #pragma unroll
            for (int g = 0; g < 4; ++g)
                acc[g] = __builtin_amdgcn_mfma_f32_16x16x32_bf16(wf[g][ks], xf[ks], acc[g], 0, 0, 0);

        bool live = (t < len);
        #pragma unroll
        for (int reg = 0; reg < 4; ++reg) {
            float iv = sigm(acc[0][reg]);
            float fv = sigm(acc[1][reg]);
            float gv = fmaxf(acc[2][reg], 0.f);
            float ov = sigm(acc[3][reg]);
            float cn = fmaf(fv, creg[reg], iv * gv);
            float hn = ov * fmaxf(cn, 0.f);
            if (live) { creg[reg] = cn; hreg[reg] = hn; }
        }
        // no second barrier: double-buffer + barrier(t+1) orders reuse safely
    }

    // l2norm per batch row
    float sq = 0.f;
    #pragma unroll
    for (int reg = 0; reg < 4; ++reg) sq = fmaf(hreg[reg], hreg[reg], sq);
    sq += __shfl_xor(sq, 16, 64);
    sq += __shfl_xor(sq, 32, 64);
    if (l < 16) red8[w][ln] = sq;
    __syncthreads();
    float tot = 0.f;
    #pragma unroll
    for (int ww = 0; ww < 8; ++ww) tot += red8[ww][ln];
    float inv = rsqrtf(fmaxf(tot, 1e-12f));
    float4 o;
    o.x = hreg[0] * inv; o.y = hreg[1] * inv; o.z = hreg[2] * inv; o.w = hreg[3] * inv;
    *(float4*)&qe_out[(size_t)(b0 + ln) * D_ + d0] = o;
}

// ---------------------------------------------------------------------------
__global__ __launch_bounds__(256) void loss_kernel(
    const float* __restrict__ te, const float* __restrict__ qe,
    const float* __restrict__ labels, float* __restrict__ partial)
{
    const int tid = threadIdx.x;
    const int b   = blockIdx.x * 256 + tid;
    float dsum = 0.f;
    #pragma unroll 8
    for (int k4 = 0; k4 < 32; ++k4) {
        float4 a = *(const float4*)&qe[(size_t)b * D_ + k4 * 4];
        float4 c = *(const float4*)&te[(size_t)b * D_ + k4 * 4];
        float dx = a.x - c.x, dy = a.y - c.y, dz = a.z - c.z, dw = a.w - c.w;
        dsum += dx * dx + dy * dy + dz * dz + dw * dw;
    }
    float lab = labels[b];
    float ds  = sqrtf(dsum);
    float ml  = fmaxf(0.f, 1.f - ds);
    float loss = lab * dsum + (1.f - lab) * ml * ml;

    __shared__ float red[256];
    red[tid] = loss;
    __syncthreads();
    for (int s = 128; s > 0; s >>= 1) {
        if (tid < s) red[tid] += red[tid + s];
        __syncthreads();
    }
    if (tid == 0) partial[blockIdx.x] = red[0];
}

__global__ void final_kernel(const float* __restrict__ partial, float* __restrict__ out)
{
    const int tid = threadIdx.x;   // 64 threads
    float v = (tid < 16) ? partial[tid] : 0.f;
    #pragma unroll
    for (int s = 32; s > 0; s >>= 1) v += __shfl_xor(v, s, 64);
    if (tid == 0) out[0] = 0.5f * v / (float)B_;
}

// ---------------------------------------------------------------------------
extern "C" void kernel_launch(void* const* d_in, const int* in_sizes, int n_in,
                              void* d_out, int out_size, void* d_ws, size_t ws_size,
                              hipStream_t stream)
{
    const float* q      = (const float*)d_in[0];
    const int*   qlen   = (const int*)d_in[1];
    const float* header = (const float*)d_in[2];
    const float* tword  = (const float*)d_in[3];
    const int*   ncols  = (const int*)d_in[4];
    const float* masks  = (const float*)d_in[5];
    const float* labels = (const float*)d_in[6];
    const float* W1     = (const float*)d_in[7];
    const float* b1     = (const float*)d_in[8];
    const float* W2     = (const float*)d_in[9];
    const float* b2     = (const float*)d_in[10];
    const float* Wx     = (const float*)d_in[11];
    const float* Wh     = (const float*)d_in[12];
    const float* bl     = (const float*)d_in[13];
    float* out = (float*)d_out;

    float* te      = (float*)d_ws;
    float* qe      = te + (size_t)B_ * D_;
    float* partial = qe + (size_t)B_ * D_;
    short* W1T     = (short*)(partial + 16);          // 192*256
    short* W2T     = W1T + 192 * 256;                 // 128*192
    short* WTl     = W2T + 128 * 192;                 // 512*256

    prep_kernel<<<512, 256, 0, stream>>>(W1, W2, Wx, Wh, W1T, W2T, WTl);
    table_kernel<<<B_, 256, 0, stream>>>(header, tword, masks, ncols, W1T, b1, W2T, b2, te);
    lstm_kernel<<<B_ / 16, 512, 0, stream>>>(q, qlen, WTl, bl, qe);
    loss_kernel<<<B_ / 256, 256, 0, stream>>>(te, qe, labels, partial);
    final_kernel<<<1, 64, 0, stream>>>(partial, out);
}